// Round 8
// baseline (422.267 us; speedup 1.0000x reference)
//
#include <hip/hip_runtime.h>
#include <hip/hip_bf16.h>

typedef __attribute__((ext_vector_type(8))) short short8;
typedef __attribute__((ext_vector_type(4))) float f32x4;
typedef __attribute__((ext_vector_type(2))) float f32x2;
typedef __attribute__((ext_vector_type(4))) unsigned short us4;

// ---- workspace layout (bytes) ----
#define WS_ZE     0u           // bf16 hi  [B][N][64] : 1 MB
#define WS_ZELO   (1u<<20)     // bf16 lo  [B][N][64] : 1 MB
#define WS_B1H    (2u<<20)     // matmul1 A-frag image hi: (k*32+t)*2048 + f*1024 + chunk*16 : 1 MB
#define WS_B1L    (3u<<20)     // matmul1 A-frag image lo : 1 MB
#define WS_B2     (4u<<20)     // matmul2 A-frag image (hi): k*65536 + ((h*8+w)*4+m)*1024 + chunk*16 : 1 MB
#define WS_ZN2    (5u<<20)     // f32 [B][N] 32 KB
#define WS_BS2    ((5u<<20)+32768u) // f32 [K][S] 32 KB
#define WS_ZQP    (6u<<20)     // f32 partial zq: kg*2MB + [B][N][64] : 4 MB

__device__ __forceinline__ unsigned short f2bf(float x) {
  __hip_bfloat16 h = __float2bfloat16(x);
  return __builtin_bit_cast(unsigned short, h);
}
__device__ __forceinline__ float bf2f(unsigned short u) {
  union { unsigned int i; float f; } x; x.i = ((unsigned int)u) << 16; return x.f;
}

// ---------------- prep: ze -> bf16 hi/lo + row norms (1 thread / row) ----------------
__global__ __launch_bounds__(256) void prep_ze_k(const float* __restrict__ ze,
                                                 char* __restrict__ ws) {
  int t = blockIdx.x * 256 + threadIdx.x;     // one per (b,n), 8192
  if (t >= 8 * 1024) return;
  const f32x4* row = (const f32x4*)(ze + t * 64);
  unsigned short* dh = (unsigned short*)(ws + WS_ZE) + t * 64;
  unsigned short* dl = (unsigned short*)(ws + WS_ZELO) + t * 64;
  float s = 0.f;
#pragma unroll
  for (int c = 0; c < 8; ++c) {
    const f32x4 v0 = row[2 * c], v1 = row[2 * c + 1];
    union { unsigned short u[8]; short8 v; } H, L;
#pragma unroll
    for (int r = 0; r < 4; ++r) {
      float a = v0[r]; s += a * a;
      unsigned short h = f2bf(a); H.u[r] = h; L.u[r] = f2bf(a - bf2f(h));
      float b = v1[r]; s += b * b;
      unsigned short h2 = f2bf(b); H.u[4 + r] = h2; L.u[4 + r] = f2bf(b - bf2f(h2));
    }
    *(short8*)(dh + c * 8) = H.v;
    *(short8*)(dl + c * 8) = L.v;
  }
  ((float*)(ws + WS_ZN2))[t] = s;
}

// ---------------- prep: book norms + precision (1 thread / row) ----------------
__global__ __launch_bounds__(256) void prep_bnorm_k(const float* __restrict__ books,
                                                    const float* __restrict__ lpq,
                                                    char* __restrict__ ws,
                                                    float* __restrict__ d_out) {
  int t = blockIdx.x * 256 + threadIdx.x;     // one per (k,s), 8192
  if (t == 0) d_out[524288] = 0.5f / fmaxf(expf(lpq[0]), 1e-10f);
  if (t >= 16 * 512) return;
  const f32x4* row = (const f32x4*)(books + t * 64);
  float s = 0.f;
#pragma unroll
  for (int c = 0; c < 16; ++c) {
    const f32x4 v = row[c];
#pragma unroll
    for (int r = 0; r < 4; ++r) s += v[r] * v[r];
  }
  ((float*)(ws + WS_BS2))[t] = s;
}

// ---------------- prep: matmul1 A-frag images (1 thread / 16B chunk) ----------------
__global__ __launch_bounds__(256) void prep_b1_k(const float* __restrict__ books,
                                                 char* __restrict__ ws) {
  int t = blockIdx.x * 256 + threadIdx.x;     // 65536
  const int sl = t & 15, g = (t >> 4) & 3, f = (t >> 6) & 1, tt = (t >> 7) & 31, k = t >> 12;
  const float* src = books + ((k * 512 + tt * 16 + sl) * 64 + f * 32 + g * 8);
  const f32x4 v0 = *(const f32x4*)(src);
  const f32x4 v1 = *(const f32x4*)(src + 4);
  union { unsigned short u[8]; short8 v; } H, L;
#pragma unroll
  for (int r = 0; r < 4; ++r) {
    unsigned short h = f2bf(v0[r]); H.u[r] = h; L.u[r] = f2bf(v0[r] - bf2f(h));
    unsigned short h2 = f2bf(v1[r]); H.u[4 + r] = h2; L.u[4 + r] = f2bf(v1[r] - bf2f(h2));
  }
  const int off = (k * 32 + tt) * 2048 + f * 1024 + (sl + g * 16) * 16;
  *(short8*)(ws + WS_B1H + off) = H.v;
  *(short8*)(ws + WS_B1L + off) = L.v;
}

// ---------------- prep: matmul2 A-frag image (1 thread / 16B chunk) ----------------
__global__ __launch_bounds__(256) void prep_b2_k(const float* __restrict__ books,
                                                 char* __restrict__ ws) {
  int t = blockIdx.x * 256 + threadIdx.x;     // 65536
  const int l15 = t & 15, sub = (t >> 4) & 3, m = (t >> 6) & 3, w = (t >> 8) & 7,
            hh = (t >> 11) & 1, k = t >> 12;
  const float* src = books + ((k * 512 + hh * 256 + w * 32 + sub * 8) * 64 + m * 16 + l15);
  union { unsigned short u[8]; short8 v; } H;
#pragma unroll
  for (int j = 0; j < 8; ++j) H.u[j] = f2bf(src[j * 64]);
  *(short8*)(ws + WS_B2 + k * 65536 + ((hh * 8 + w) * 4 + m) * 1024 + (l15 + sub * 16) * 16) = H.v;
}

// ---------------- zq partial reduce ----------------
__global__ __launch_bounds__(256) void zq_red_k(const char* __restrict__ ws,
                                                float* __restrict__ d_out) {
  int t = blockIdx.x * 256 + threadIdx.x;     // 131072 x f32x4
  const f32x4 a = *(const f32x4*)(ws + WS_ZQP + t * 16);
  const f32x4 b = *(const f32x4*)(ws + WS_ZQP + (1u << 21) + t * 16);
  *(f32x4*)(d_out + t * 4) = a + b;
}

// ---------------- main ----------------
__global__ __launch_bounds__(512, 6)
void gvq_main(const float* __restrict__ gum, const float* __restrict__ cprobs,
              const float* __restrict__ lpq, char* __restrict__ ws,
              float* __restrict__ d_out) {
  __shared__ char lds[36864];
  // encb double buffer: 2 x 16 KB; scr double buffer: 2 x 2 KB (128 f32x4 each)
  f32x4* scrb = (f32x4*)(lds + 32768);

  const int tid  = threadIdx.x;
  const int lane = tid & 63;
  const int wave = tid >> 6;       // 0..7
  const int l15  = lane & 15;      // = n within tile (MFMA D col)
  const int g4   = lane >> 4;      // 0..3

  const int bid = blockIdx.x;      // 1024 blocks
  const int kg  = bid & 1;
  const int bt  = bid >> 1;
  const int b   = bt >> 6;
  const int n0  = (bt & 63) * 16;

  const float prec  = 0.5f / fmaxf(expf(lpq[0]), 1e-10f);
  const float prec2 = 2.0f * prec;

  const unsigned short* zh = (const unsigned short*)(ws + WS_ZE)   + (b * 1024 + n0 + l15) * 64;
  const unsigned short* zl = (const unsigned short*)(ws + WS_ZELO) + (b * 1024 + n0 + l15) * 64;
  const short8 zf0h = *(const short8*)(zh + g4 * 8);
  const short8 zf1h = *(const short8*)(zh + 32 + g4 * 8);
  const short8 zf0l = *(const short8*)(zl + g4 * 8);
  const short8 zf1l = *(const short8*)(zl + 32 + g4 * 8);
  const float zn2p = ((const float*)(ws + WS_ZN2))[b * 1024 + n0 + l15] * prec;

  const unsigned swzr = (unsigned)(l15 & 7) << 4;

  f32x4 zacc[4] = {{0,0,0,0},{0,0,0,0},{0,0,0,0},{0,0,0,0}};

  // element layout per lane: s = wave*64 + i*16 + g4*4 + r  (16 elems, n = l15)
  const long gbase0 = ((long)(b * 16) * 1024 + (n0 + l15)) * 512 + wave * 64 + g4 * 4;

#pragma unroll 1
  for (int kk = 0; kk < 8; ++kk) {
    const int k = kg * 8 + kk;
    const float cp = cprobs[b * 16 + k];
    const char* b1h = ws + WS_B1H + k * 65536;
    const char* b1l = ws + WS_B1L + k * 65536;
    const char* b2  = ws + WS_B2  + k * 65536;
    const float* bs2k = (const float*)(ws + WS_BS2) + k * 512;
    const long gb = gbase0 + (long)k * 524288;
    char* encb = lds + (kk & 1) * 16384;
    char* encrow = encb + l15 * 1024;
    f32x4* scr = scrb + (kk & 1) * 128;

    // ---- gumbel loads (land under phase A) ----
    const float* up = gum + gb;
    f32x4 uu[4];
#pragma unroll
    for (int i = 0; i < 4; ++i) uu[i] = *(const f32x4*)(up + i * 16);

    // ---- phase A: logits in registers (3-term hi/lo bf16 MFMA) ----
    f32x4 lv[4];
#pragma unroll
    for (int i = 0; i < 4; ++i) {
      const int t = wave * 4 + i;                 // stile 0..31
      const char* bh = b1h + t * 2048 + lane * 16;
      const char* bl = b1l + t * 2048 + lane * 16;
      const short8 a0h = *(const short8*)(bh);
      const short8 a1h = *(const short8*)(bh + 1024);
      const short8 a0l = *(const short8*)(bl);
      const short8 a1l = *(const short8*)(bl + 1024);
      f32x4 c = {0.f, 0.f, 0.f, 0.f};
      c = __builtin_amdgcn_mfma_f32_16x16x32_bf16(a0h, zf0h, c, 0, 0, 0);
      c = __builtin_amdgcn_mfma_f32_16x16x32_bf16(a1h, zf1h, c, 0, 0, 0);
      c = __builtin_amdgcn_mfma_f32_16x16x32_bf16(a0h, zf0l, c, 0, 0, 0);
      c = __builtin_amdgcn_mfma_f32_16x16x32_bf16(a1h, zf1l, c, 0, 0, 0);
      c = __builtin_amdgcn_mfma_f32_16x16x32_bf16(a0l, zf0h, c, 0, 0, 0);
      c = __builtin_amdgcn_mfma_f32_16x16x32_bf16(a1l, zf1h, c, 0, 0, 0);
      const f32x4 bs2v = *(const f32x4*)(bs2k + t * 16 + g4 * 4);
#pragma unroll
      for (int r = 0; r < 4; ++r)
        lv[i][r] = fmaf(c[r], prec2, fmaf(bs2v[r], -prec, -zn2p));
    }

    // ---- pass 1: gumbel transform (into uu) + wave-local maxes ----
    float m1w = -1e30f, m2w = -1e30f;
#pragma unroll
    for (int i = 0; i < 4; ++i)
#pragma unroll
      for (int r = 0; r < 4; ++r) {
        const float gg = -__logf(-__logf(uu[i][r] + 1e-10f) + 1e-10f);
        const float a = (lv[i][r] + gg) * 2.0f;     // /TEMPERATURE(0.5)
        uu[i][r] = a;
        m1w = fmaxf(m1w, lv[i][r]);
        m2w = fmaxf(m2w, a);
      }
    m1w = fmaxf(m1w, __shfl_xor(m1w, 16)); m1w = fmaxf(m1w, __shfl_xor(m1w, 32));
    m2w = fmaxf(m2w, __shfl_xor(m2w, 16)); m2w = fmaxf(m2w, __shfl_xor(m2w, 32));

    // ---- pass 2: exps; enc (wave-local scale) packed to LDS pre-barrier ----
    float z1 = 0.f, z2 = 0.f;
#pragma unroll
    for (int i = 0; i < 4; ++i) {
      us4 ev;
#pragma unroll
      for (int r = 0; r < 4; ++r) {
        z1 += __expf(lv[i][r] - m1w);
        const float e2 = __expf(uu[i][r] - m2w);
        z2 += e2;
        ev[r] = f2bf(e2);
      }
      *(us4*)(encrow + (((unsigned)(wave * 128 + i * 32 + g4 * 8)) ^ swzr)) = ev;
    }
    z1 += __shfl_xor(z1, 16); z1 += __shfl_xor(z1, 32);
    z2 += __shfl_xor(z2, 16); z2 += __shfl_xor(z2, 32);
    if (g4 == 0) scr[wave * 16 + l15] = (f32x4){m1w, m2w, z1, z2};
    __syncthreads();                   // single barrier per iter

    // ---- merge across waves ----
    float m1, m2, zz1, zz2;
    {
      const f32x4 pa = scr[g4 * 16 + l15];
      const f32x4 pb = scr[(g4 + 4) * 16 + l15];
      m1 = fmaxf(pa.x, pb.x); m2 = fmaxf(pa.y, pb.y);
      m1 = fmaxf(m1, __shfl_xor(m1, 16)); m1 = fmaxf(m1, __shfl_xor(m1, 32));
      m2 = fmaxf(m2, __shfl_xor(m2, 16)); m2 = fmaxf(m2, __shfl_xor(m2, 32));
      zz1 = pa.z * __expf(pa.x - m1) + pb.z * __expf(pb.x - m1);
      zz2 = pa.w * __expf(pa.y - m2) + pb.w * __expf(pb.y - m2);
      zz1 += __shfl_xor(zz1, 16); zz1 += __shfl_xor(zz1, 32);
      zz2 += __shfl_xor(zz2, 16); zz2 += __shfl_xor(zz2, 32);
    }
    const float c1 = m1 + __logf(zz1);           // prob = exp(lv-c1), log_prob = lv-c1
    const float s2 = cp / zz2;

    // ---- phase C: per-h matmul into cacc, fold slice-correction * s2 ----
#pragma unroll
    for (int h = 0; h < 2; ++h) {
      const short8 bf = *(const short8*)(encrow +
          (((unsigned)(h * 512 + wave * 64 + g4 * 16)) ^ swzr));
      f32x4 cacc[4] = {{0,0,0,0},{0,0,0,0},{0,0,0,0},{0,0,0,0}};
#pragma unroll
      for (int m = 0; m < 4; ++m) {
        const short8 af = *(const short8*)(b2 + ((h * 8 + wave) * 4 + m) * 1024 + lane * 16);
        cacc[m] = __builtin_amdgcn_mfma_f32_16x16x32_bf16(af, bf, cacc[m], 0, 0, 0);
      }
      // writer wave of this B-slice: w' = h*4 + wave/2; per-lane n = l15
      const float fh = __expf(scr[(h * 4 + (wave >> 1)) * 16 + l15].y - m2) * s2;
#pragma unroll
      for (int m = 0; m < 4; ++m)
#pragma unroll
        for (int r = 0; r < 4; ++r) zacc[m][r] = fmaf(cacc[m][r], fh, zacc[m][r]);
    }

    // ---- prob/log_prob stores ----
    float* pp = d_out + 524289 + gb;
    float* pl = pp + 67108864;
#pragma unroll
    for (int i = 0; i < 4; ++i) {
      f32x4 pv, lpv;
#pragma unroll
      for (int r = 0; r < 4; ++r) {
        lpv[r] = lv[i][r] - c1;
        pv[r]  = __expf(lpv[r]);
      }
      *(f32x4*)(pp + i * 16) = pv;
      *(f32x4*)(pl + i * 16) = lpv;
    }
  }

  // ---- zq cross-wave reduce + partial write ----
  __syncthreads();
#pragma unroll
  for (int m = 0; m < 4; ++m)
    *(f32x4*)(lds + wave * 4096 + l15 * 256 + m * 64 + g4 * 16) = zacc[m];
  __syncthreads();
  const int e = tid * 2;                    // 0..1022, covers 16*64 elems
  f32x2 acc = {0.f, 0.f};
#pragma unroll
  for (int w = 0; w < 8; ++w) acc += *(const f32x2*)(lds + w * 4096 + e * 4);
  *(f32x2*)(ws + WS_ZQP + (unsigned)kg * (1u << 21) +
            (((unsigned)(b * 1024 + n0)) * 64 + e) * 4) = acc;
}

extern "C" void kernel_launch(void* const* d_in, const int* in_sizes, int n_in,
                              void* d_out, int out_size, void* d_ws, size_t ws_size,
                              hipStream_t stream) {
  (void)in_sizes; (void)n_in; (void)out_size; (void)ws_size;
  const float* ze     = (const float*)d_in[0];
  const float* cprobs = (const float*)d_in[1];
  const float* books  = (const float*)d_in[2];
  const float* lpq    = (const float*)d_in[3];
  const float* gum    = (const float*)d_in[4];
  float* out = (float*)d_out;
  char* ws = (char*)d_ws;
  hipLaunchKernelGGL(prep_ze_k,    dim3(32),   dim3(256), 0, stream, ze, ws);
  hipLaunchKernelGGL(prep_bnorm_k, dim3(32),   dim3(256), 0, stream, books, lpq, ws, out);
  hipLaunchKernelGGL(prep_b1_k,    dim3(256),  dim3(256), 0, stream, books, ws);
  hipLaunchKernelGGL(prep_b2_k,    dim3(256),  dim3(256), 0, stream, books, ws);
  hipLaunchKernelGGL(gvq_main,     dim3(1024), dim3(512), 0, stream, gum, cprobs, lpq, ws, out);
  hipLaunchKernelGGL(zq_red_k,     dim3(512),  dim3(256), 0, stream, ws, out);
}

// Round 9
// 308.223 us; speedup vs baseline: 1.3700x; 1.3700x over previous
//
#include <hip/hip_runtime.h>
#include <hip/hip_bf16.h>

typedef __attribute__((ext_vector_type(8))) short short8;
typedef __attribute__((ext_vector_type(4))) float f32x4;
typedef __attribute__((ext_vector_type(2))) float f32x2;
typedef __attribute__((ext_vector_type(4))) unsigned short us4;

// ---- workspace layout (bytes) ----
#define WS_ZE     0u           // bf16 hi  [B][N][64] : 1 MB
#define WS_ZELO   (1u<<20)     // bf16 lo  [B][N][64] : 1 MB
#define WS_B1H    (2u<<20)     // matmul1 A-frag image hi: (k*32+t)*2048 + f*1024 + chunk*16 : 1 MB
#define WS_B1L    (3u<<20)     // matmul1 A-frag image lo : 1 MB
#define WS_B2     (4u<<20)     // matmul2 A-frag image (hi): k*65536 + ((h*8+w)*4+m)*1024 + chunk*16 : 1 MB
#define WS_ZN2    (5u<<20)     // f32 [B][N] 32 KB
#define WS_BS2    ((5u<<20)+32768u) // f32 [K][S] 32 KB
#define WS_ZQP    (6u<<20)     // f32 partial zq: kg*2MB + [B][N][64] : 4 MB

__device__ __forceinline__ unsigned short f2bf(float x) {
  __hip_bfloat16 h = __float2bfloat16(x);
  return __builtin_bit_cast(unsigned short, h);
}
__device__ __forceinline__ float bf2f(unsigned short u) {
  union { unsigned int i; float f; } x; x.i = ((unsigned int)u) << 16; return x.f;
}

// ---------------- prep: ze -> bf16 hi/lo + row norms (1 thread / row) ----------------
__global__ __launch_bounds__(256) void prep_ze_k(const float* __restrict__ ze,
                                                 char* __restrict__ ws) {
  int t = blockIdx.x * 256 + threadIdx.x;     // one per (b,n), 8192
  if (t >= 8 * 1024) return;
  const f32x4* row = (const f32x4*)(ze + t * 64);
  unsigned short* dh = (unsigned short*)(ws + WS_ZE) + t * 64;
  unsigned short* dl = (unsigned short*)(ws + WS_ZELO) + t * 64;
  float s = 0.f;
#pragma unroll
  for (int c = 0; c < 8; ++c) {
    const f32x4 v0 = row[2 * c], v1 = row[2 * c + 1];
    union { unsigned short u[8]; short8 v; } H, L;
#pragma unroll
    for (int r = 0; r < 4; ++r) {
      float a = v0[r]; s += a * a;
      unsigned short h = f2bf(a); H.u[r] = h; L.u[r] = f2bf(a - bf2f(h));
      float b = v1[r]; s += b * b;
      unsigned short h2 = f2bf(b); H.u[4 + r] = h2; L.u[4 + r] = f2bf(b - bf2f(h2));
    }
    *(short8*)(dh + c * 8) = H.v;
    *(short8*)(dl + c * 8) = L.v;
  }
  ((float*)(ws + WS_ZN2))[t] = s;
}

// ---------------- prep: book norms + precision (1 thread / row) ----------------
__global__ __launch_bounds__(256) void prep_bnorm_k(const float* __restrict__ books,
                                                    const float* __restrict__ lpq,
                                                    char* __restrict__ ws,
                                                    float* __restrict__ d_out) {
  int t = blockIdx.x * 256 + threadIdx.x;     // one per (k,s), 8192
  if (t == 0) d_out[524288] = 0.5f / fmaxf(expf(lpq[0]), 1e-10f);
  if (t >= 16 * 512) return;
  const f32x4* row = (const f32x4*)(books + t * 64);
  float s = 0.f;
#pragma unroll
  for (int c = 0; c < 16; ++c) {
    const f32x4 v = row[c];
#pragma unroll
    for (int r = 0; r < 4; ++r) s += v[r] * v[r];
  }
  ((float*)(ws + WS_BS2))[t] = s;
}

// ---------------- prep: matmul1 A-frag images (1 thread / 16B chunk) ----------------
__global__ __launch_bounds__(256) void prep_b1_k(const float* __restrict__ books,
                                                 char* __restrict__ ws) {
  int t = blockIdx.x * 256 + threadIdx.x;     // 65536
  const int sl = t & 15, g = (t >> 4) & 3, f = (t >> 6) & 1, tt = (t >> 7) & 31, k = t >> 12;
  const float* src = books + ((k * 512 + tt * 16 + sl) * 64 + f * 32 + g * 8);
  const f32x4 v0 = *(const f32x4*)(src);
  const f32x4 v1 = *(const f32x4*)(src + 4);
  union { unsigned short u[8]; short8 v; } H, L;
#pragma unroll
  for (int r = 0; r < 4; ++r) {
    unsigned short h = f2bf(v0[r]); H.u[r] = h; L.u[r] = f2bf(v0[r] - bf2f(h));
    unsigned short h2 = f2bf(v1[r]); H.u[4 + r] = h2; L.u[4 + r] = f2bf(v1[r] - bf2f(h2));
  }
  const int off = (k * 32 + tt) * 2048 + f * 1024 + (sl + g * 16) * 16;
  *(short8*)(ws + WS_B1H + off) = H.v;
  *(short8*)(ws + WS_B1L + off) = L.v;
}

// ---------------- prep: matmul2 A-frag image (1 thread / 16B chunk) ----------------
__global__ __launch_bounds__(256) void prep_b2_k(const float* __restrict__ books,
                                                 char* __restrict__ ws) {
  int t = blockIdx.x * 256 + threadIdx.x;     // 65536
  const int l15 = t & 15, sub = (t >> 4) & 3, m = (t >> 6) & 3, w = (t >> 8) & 7,
            hh = (t >> 11) & 1, k = t >> 12;
  const float* src = books + ((k * 512 + hh * 256 + w * 32 + sub * 8) * 64 + m * 16 + l15);
  union { unsigned short u[8]; short8 v; } H;
#pragma unroll
  for (int j = 0; j < 8; ++j) H.u[j] = f2bf(src[j * 64]);
  *(short8*)(ws + WS_B2 + k * 65536 + ((hh * 8 + w) * 4 + m) * 1024 + (l15 + sub * 16) * 16) = H.v;
}

// ---------------- zq partial reduce ----------------
__global__ __launch_bounds__(256) void zq_red_k(const char* __restrict__ ws,
                                                float* __restrict__ d_out) {
  int t = blockIdx.x * 256 + threadIdx.x;     // 131072 x f32x4
  const f32x4 a = *(const f32x4*)(ws + WS_ZQP + t * 16);
  const f32x4 b = *(const f32x4*)(ws + WS_ZQP + (1u << 21) + t * 16);
  *(f32x4*)(d_out + t * 4) = a + b;
}

// ---------------- main ----------------
__global__ __launch_bounds__(512, 4)
void gvq_main(const float* __restrict__ gum, const float* __restrict__ cprobs,
              const float* __restrict__ lpq, char* __restrict__ ws,
              float* __restrict__ d_out) {
  __shared__ char lds[36864];
  // encb double buffer: 2 x 16 KB; scr double buffer: 2 x 2 KB (128 f32x4 each)
  f32x4* scrb = (f32x4*)(lds + 32768);

  const int tid  = threadIdx.x;
  const int lane = tid & 63;
  const int wave = tid >> 6;       // 0..7
  const int l15  = lane & 15;      // = n within tile (MFMA D col)
  const int g4   = lane >> 4;      // 0..3

  const int bid = blockIdx.x;      // 1024 blocks
  const int kg  = bid & 1;
  const int bt  = bid >> 1;
  const int b   = bt >> 6;
  const int n0  = (bt & 63) * 16;

  const float prec  = 0.5f / fmaxf(expf(lpq[0]), 1e-10f);
  const float prec2 = 2.0f * prec;

  const unsigned short* zh = (const unsigned short*)(ws + WS_ZE)   + (b * 1024 + n0 + l15) * 64;
  const unsigned short* zl = (const unsigned short*)(ws + WS_ZELO) + (b * 1024 + n0 + l15) * 64;
  const short8 zf0h = *(const short8*)(zh + g4 * 8);
  const short8 zf1h = *(const short8*)(zh + 32 + g4 * 8);
  const short8 zf0l = *(const short8*)(zl + g4 * 8);
  const short8 zf1l = *(const short8*)(zl + 32 + g4 * 8);
  const float zn2p = ((const float*)(ws + WS_ZN2))[b * 1024 + n0 + l15] * prec;

  const unsigned swzr = (unsigned)(l15 & 7) << 4;

  f32x4 zacc[4] = {{0,0,0,0},{0,0,0,0},{0,0,0,0},{0,0,0,0}};

  // element layout per lane: s = wave*64 + i*16 + g4*4 + r  (16 elems, n = l15)
  const long gbase0 = ((long)(b * 16) * 1024 + (n0 + l15)) * 512 + wave * 64 + g4 * 4;

#pragma unroll 1
  for (int kk = 0; kk < 8; ++kk) {
    const int k = kg * 8 + kk;
    const float cp = cprobs[b * 16 + k];
    const char* b1h = ws + WS_B1H + k * 65536;
    const char* b1l = ws + WS_B1L + k * 65536;
    const char* b2  = ws + WS_B2  + k * 65536;
    const float* bs2k = (const float*)(ws + WS_BS2) + k * 512;
    const long gb = gbase0 + (long)k * 524288;
    char* encb = lds + (kk & 1) * 16384;
    char* encrow = encb + l15 * 1024;
    f32x4* scr = scrb + (kk & 1) * 128;

    // ---- gumbel loads (land under phase A) ----
    const float* up = gum + gb;
    f32x4 uu[4];
#pragma unroll
    for (int i = 0; i < 4; ++i) uu[i] = *(const f32x4*)(up + i * 16);

    // ---- phase A: logits in registers (3-term hi/lo bf16 MFMA) ----
    f32x4 lv[4];
#pragma unroll
    for (int i = 0; i < 4; ++i) {
      const int t = wave * 4 + i;                 // stile 0..31
      const char* bh = b1h + t * 2048 + lane * 16;
      const char* bl = b1l + t * 2048 + lane * 16;
      const short8 a0h = *(const short8*)(bh);
      const short8 a1h = *(const short8*)(bh + 1024);
      const short8 a0l = *(const short8*)(bl);
      const short8 a1l = *(const short8*)(bl + 1024);
      f32x4 c = {0.f, 0.f, 0.f, 0.f};
      c = __builtin_amdgcn_mfma_f32_16x16x32_bf16(a0h, zf0h, c, 0, 0, 0);
      c = __builtin_amdgcn_mfma_f32_16x16x32_bf16(a1h, zf1h, c, 0, 0, 0);
      c = __builtin_amdgcn_mfma_f32_16x16x32_bf16(a0h, zf0l, c, 0, 0, 0);
      c = __builtin_amdgcn_mfma_f32_16x16x32_bf16(a1h, zf1l, c, 0, 0, 0);
      c = __builtin_amdgcn_mfma_f32_16x16x32_bf16(a0l, zf0h, c, 0, 0, 0);
      c = __builtin_amdgcn_mfma_f32_16x16x32_bf16(a1l, zf1h, c, 0, 0, 0);
      const f32x4 bs2v = *(const f32x4*)(bs2k + t * 16 + g4 * 4);
#pragma unroll
      for (int r = 0; r < 4; ++r)
        lv[i][r] = fmaf(c[r], prec2, fmaf(bs2v[r], -prec, -zn2p));
    }

    // ---- pass 1: gumbel transform (into uu) + wave-local maxes ----
    float m1w = -1e30f, m2w = -1e30f;
#pragma unroll
    for (int i = 0; i < 4; ++i)
#pragma unroll
      for (int r = 0; r < 4; ++r) {
        const float gg = -__logf(-__logf(uu[i][r] + 1e-10f) + 1e-10f);
        const float a = (lv[i][r] + gg) * 2.0f;     // /TEMPERATURE(0.5)
        uu[i][r] = a;
        m1w = fmaxf(m1w, lv[i][r]);
        m2w = fmaxf(m2w, a);
      }
    m1w = fmaxf(m1w, __shfl_xor(m1w, 16)); m1w = fmaxf(m1w, __shfl_xor(m1w, 32));
    m2w = fmaxf(m2w, __shfl_xor(m2w, 16)); m2w = fmaxf(m2w, __shfl_xor(m2w, 32));

    // ---- pass 2: exps; enc (wave-local scale) packed to LDS pre-barrier ----
    float z1 = 0.f, z2 = 0.f;
#pragma unroll
    for (int i = 0; i < 4; ++i) {
      us4 ev;
#pragma unroll
      for (int r = 0; r < 4; ++r) {
        z1 += __expf(lv[i][r] - m1w);
        const float e2 = __expf(uu[i][r] - m2w);
        z2 += e2;
        ev[r] = f2bf(e2);
      }
      *(us4*)(encrow + (((unsigned)(wave * 128 + i * 32 + g4 * 8)) ^ swzr)) = ev;
    }
    z1 += __shfl_xor(z1, 16); z1 += __shfl_xor(z1, 32);
    z2 += __shfl_xor(z2, 16); z2 += __shfl_xor(z2, 32);
    if (g4 == 0) scr[wave * 16 + l15] = (f32x4){m1w, m2w, z1, z2};
    __syncthreads();                   // single barrier per iter

    // ---- merge across waves ----
    float m1, m2, zz1, zz2;
    {
      const f32x4 pa = scr[g4 * 16 + l15];
      const f32x4 pb = scr[(g4 + 4) * 16 + l15];
      m1 = fmaxf(pa.x, pb.x); m2 = fmaxf(pa.y, pb.y);
      m1 = fmaxf(m1, __shfl_xor(m1, 16)); m1 = fmaxf(m1, __shfl_xor(m1, 32));
      m2 = fmaxf(m2, __shfl_xor(m2, 16)); m2 = fmaxf(m2, __shfl_xor(m2, 32));
      zz1 = pa.z * __expf(pa.x - m1) + pb.z * __expf(pb.x - m1);
      zz2 = pa.w * __expf(pa.y - m2) + pb.w * __expf(pb.y - m2);
      zz1 += __shfl_xor(zz1, 16); zz1 += __shfl_xor(zz1, 32);
      zz2 += __shfl_xor(zz2, 16); zz2 += __shfl_xor(zz2, 32);
    }
    const float c1 = m1 + __logf(zz1);           // prob = exp(lv-c1), log_prob = lv-c1
    const float s2 = cp / zz2;

    // ---- phase C: per-h matmul into cacc, fold slice-correction * s2 ----
#pragma unroll
    for (int h = 0; h < 2; ++h) {
      const short8 bf = *(const short8*)(encrow +
          (((unsigned)(h * 512 + wave * 64 + g4 * 16)) ^ swzr));
      f32x4 cacc[4] = {{0,0,0,0},{0,0,0,0},{0,0,0,0},{0,0,0,0}};
#pragma unroll
      for (int m = 0; m < 4; ++m) {
        const short8 af = *(const short8*)(b2 + ((h * 8 + wave) * 4 + m) * 1024 + lane * 16);
        cacc[m] = __builtin_amdgcn_mfma_f32_16x16x32_bf16(af, bf, cacc[m], 0, 0, 0);
      }
      // writer wave of this B-slice: w' = h*4 + wave/2; per-lane n = l15
      const float fh = __expf(scr[(h * 4 + (wave >> 1)) * 16 + l15].y - m2) * s2;
#pragma unroll
      for (int m = 0; m < 4; ++m)
#pragma unroll
        for (int r = 0; r < 4; ++r) zacc[m][r] = fmaf(cacc[m][r], fh, zacc[m][r]);
    }

    // ---- prob/log_prob stores ----
    float* pp = d_out + 524289 + gb;
    float* pl = pp + 67108864;
#pragma unroll
    for (int i = 0; i < 4; ++i) {
      f32x4 pv, lpv;
#pragma unroll
      for (int r = 0; r < 4; ++r) {
        lpv[r] = lv[i][r] - c1;
        pv[r]  = __expf(lpv[r]);
      }
      *(f32x4*)(pp + i * 16) = pv;
      *(f32x4*)(pl + i * 16) = lpv;
    }
  }

  // ---- zq cross-wave reduce + partial write ----
  __syncthreads();
#pragma unroll
  for (int m = 0; m < 4; ++m)
    *(f32x4*)(lds + wave * 4096 + l15 * 256 + m * 64 + g4 * 16) = zacc[m];
  __syncthreads();
  const int e = tid * 2;                    // 0..1022, covers 16*64 elems
  f32x2 acc = {0.f, 0.f};
#pragma unroll
  for (int w = 0; w < 8; ++w) acc += *(const f32x2*)(lds + w * 4096 + e * 4);
  *(f32x2*)(ws + WS_ZQP + (unsigned)kg * (1u << 21) +
            (((unsigned)(b * 1024 + n0)) * 64 + e) * 4) = acc;
}

extern "C" void kernel_launch(void* const* d_in, const int* in_sizes, int n_in,
                              void* d_out, int out_size, void* d_ws, size_t ws_size,
                              hipStream_t stream) {
  (void)in_sizes; (void)n_in; (void)out_size; (void)ws_size;
  const float* ze     = (const float*)d_in[0];
  const float* cprobs = (const float*)d_in[1];
  const float* books  = (const float*)d_in[2];
  const float* lpq    = (const float*)d_in[3];
  const float* gum    = (const float*)d_in[4];
  float* out = (float*)d_out;
  char* ws = (char*)d_ws;
  hipLaunchKernelGGL(prep_ze_k,    dim3(32),   dim3(256), 0, stream, ze, ws);
  hipLaunchKernelGGL(prep_bnorm_k, dim3(32),   dim3(256), 0, stream, books, lpq, ws, out);
  hipLaunchKernelGGL(prep_b1_k,    dim3(256),  dim3(256), 0, stream, books, ws);
  hipLaunchKernelGGL(prep_b2_k,    dim3(256),  dim3(256), 0, stream, books, ws);
  hipLaunchKernelGGL(gvq_main,     dim3(1024), dim3(512), 0, stream, gum, cprobs, lpq, ws, out);
  hipLaunchKernelGGL(zq_red_k,     dim3(512),  dim3(256), 0, stream, ws, out);
}